// Round 5
// baseline (255.574 us; speedup 1.0000x reference)
//
#include <hip/hip_runtime.h>
#include <hip/hip_bf16.h>
#include <stdint.h>

typedef __attribute__((ext_vector_type(8)))  short short8;
typedef __attribute__((ext_vector_type(8)))  unsigned short ushort8;
typedef __attribute__((ext_vector_type(4)))  float floatx4;
typedef __attribute__((ext_vector_type(4)))  int intx4;
typedef __attribute__((ext_vector_type(4)))  unsigned short ushortx4;

static constexpr int BATCH = 4;
static constexpr int SEQ   = 2048;
static constexpr int DIM   = 1024;
static constexpr int LDQ   = 3 * DIM;  // qkv row stride

typedef __attribute__((address_space(1))) unsigned int gas_u32;
typedef __attribute__((address_space(3))) unsigned int las_u32;
typedef __attribute__((address_space(3))) const __hip_bfloat16 lds_cbf16;

__device__ __forceinline__ void async_copy16(void* lds, const void* g) {
  __builtin_amdgcn_global_load_lds((const gas_u32*)g, (las_u32*)lds, 16, 0, 0);
}

// Inline-asm ds_read_b128: invisible to backend waitcnt insertion (keeps the
// global_load_lds ring in flight). No "memory" clobbers anywhere in the hot
// loop (round-2 lesson: clobber => conservative vmcnt(0) drain per phase).
template<int OFF>
__device__ __forceinline__ short8 ds_read128(lds_cbf16* p) {
  short8 r;
  asm volatile("ds_read_b128 %0, %1 offset:%2" : "=v"(r) : "v"(p), "i"(OFF));
  return r;
}

__device__ __forceinline__ void wait_lgkm0() {
  asm volatile("s_waitcnt lgkmcnt(0)");     // bare: no memory clobber
  __builtin_amdgcn_sched_barrier(0);        // rule #18: pin MFMA behind wait
}

// T1: bijective XCD-aware block swizzle (m204). Consecutive dispatch ids
// round-robin XCDs; remap so each XCD owns a CONTIGUOUS chunk of tile space
// -> L2 panel reuse. Bijective for any n (incl. n%8 != 0).
__device__ __forceinline__ void xcd_swizzle(int& bx, int& by) {
  const int gx  = gridDim.x;
  const int n   = gx * gridDim.y;
  const int bid = blockIdx.x + gx * blockIdx.y;
  const int q = n >> 3, r = n & 7;
  const int xcd = bid & 7, idx = bid >> 3;
  const int wg = (xcd < r) ? (xcd * (q + 1) + idx)
                           : (r * (q + 1) + (xcd - r) * q + idx);
  bx = wg % gx;
  by = wg / gx;
}

// ---------------------------------------------------------------------------
// Fused canonize (per-block fp32-vs-bf16 self-detection) + zero rowsum.
// ---------------------------------------------------------------------------
__global__ __launch_bounds__(256) void canonize_all(
    const void* __restrict__ s0, const void* __restrict__ s1,
    const void* __restrict__ s2, const void* __restrict__ s3,
    const void* __restrict__ s4, const void* __restrict__ s5,
    const void* __restrict__ s6,
    __hip_bfloat16* __restrict__ xc, __hip_bfloat16* __restrict__ Wc,
    __hip_bfloat16* __restrict__ bc, float* __restrict__ rowsum)
{
  int bid = blockIdx.x;
  if (bid >= 5635) {
    const int i = (bid - 5635) * 2048 + threadIdx.x * 8;
    intx4 z = {0, 0, 0, 0};
    *(intx4*)(rowsum + i)     = z;
    *(intx4*)(rowsum + i + 4) = z;
    return;
  }
  const void* src; __hip_bfloat16* dst; int n;
  if (bid < 4096)        { src = s0; dst = xc;            n = 8388608; }
  else if (bid < 4608)   { src = s1; dst = Wc;            n = 1048576; bid -= 4096; }
  else if (bid < 5120)   { src = s2; dst = Wc + 1048576;  n = 1048576; bid -= 4608; }
  else if (bid < 5632)   { src = s3; dst = Wc + 2097152;  n = 1048576; bid -= 5120; }
  else if (bid == 5632)  { src = s4; dst = bc;            n = 1024;    bid = 0; }
  else if (bid == 5633)  { src = s5; dst = bc + 1024;     n = 1024;    bid = 0; }
  else                   { src = s6; dst = bc + 2048;     n = 1024;    bid = 0; }

  __shared__ int cnt;
  if (threadIdx.x == 0) cnt = 0;
  __syncthreads();

  const int i = (bid * 256 + threadIdx.x) * 8;
  ushort8 v = {};
  int local = 0;
  if (i < n) {
    v = *(const ushort8*)((const unsigned short*)src + i);
#pragma unroll
    for (int j = 0; j < 8; j++) {
      unsigned e = (v[j] >> 7) & 0xFFu;
      local += (e >= 0x90u) ? 1 : 0;
    }
  }
  if (local) atomicAdd(&cnt, local);
  __syncthreads();
  if (i >= n) return;

  if (cnt > 4) {  // fp32 input: convert
    const float* s = (const float*)src + i;
    ushort8 o;
#pragma unroll
    for (int j = 0; j < 8; j++) {
      __hip_bfloat16 h = (__hip_bfloat16)s[j];
      o[j] = *(const unsigned short*)&h;
    }
    *(ushort8*)((unsigned short*)dst + i) = o;
  } else {        // already bf16: copy the probed data
    *(ushort8*)((unsigned short*)dst + i) = v;
  }
}

// ---------------------------------------------------------------------------
// 16-MFMA cluster: acc rows MI0,MI0+1 x 4 ni x 2 k-slices.
// ---------------------------------------------------------------------------
template<int MI0, int MR>
__device__ __forceinline__ void mfma_quad(floatx4 (&acc)[MR][4],
    const short8 (&fa)[2][2], const short8 (&fb)[2][4]) {
#pragma unroll
  for (int i = 0; i < 2; i++)
#pragma unroll
    for (int ni = 0; ni < 4; ni++)
#pragma unroll
      for (int ks = 0; ks < 2; ks++)
        acc[MI0 + i][ni] = __builtin_amdgcn_mfma_f32_16x16x32_bf16(
            fa[ks][i], fb[ks][ni], acc[MI0 + i][ni], 0, 0, 0);
}

// ---------------------------------------------------------------------------
// NT GEMM, 256x256 tile, BK=64, 512 threads = 8 waves (2M x 4N), per-wave
// 128x64 output, 4 MFMA quads per K-tile, TWO barriers per K-tile.
// Round-5 prefetch timing (max latency cover):
//   top of tile t : burst-read fb(8)+faA(4); stage A(t+1) BOTH halves
//                   (earliest WAR-legal point; ~full-tile cover to boundary)
//   quad0 [shadow: faB reads]  quad1 [shadow: faA2 reads]
//   BARRIER-1  (all waves' fb reads certified -> B-region of buf reusable)
//   stage B(t+2) BOTH halves   (1.5-tile cover to its boundary)
//   quad2 [shadow: faB2 reads] quad3
//   sched_barrier; vmcnt(4); s_barrier   (oldest 12: B(t+1)4,A(t+1)4,B(t+2)4
//                                         -> waits t+1 landed, keeps B(t+2))
// WAR: stageA->buf^1 legal after the t-1 boundary barrier; stageB->buf legal
// after BARRIER-1. RAW: per-wave vmcnt(4) BEFORE the boundary barrier.
// Fragment slot (quad^(lm>>1)) + staging xor (tid&7)^((tid>>4)&7) are
// row-mod-16 consistent -> 0 LDS bank conflicts (measured).
// EPI: 0 = +bias[col] -> bf16 ; 1 = exp(acc/32) -> bf16 + rowsum atomics
// ---------------------------------------------------------------------------
template<int EPI>
__global__ __launch_bounds__(512, 2) void gemm256(
    const __hip_bfloat16* __restrict__ A,
    const __hip_bfloat16* __restrict__ B,
    const __hip_bfloat16* __restrict__ bias,
    float* __restrict__ rowsum,
    void* __restrict__ Cout,
    int M, int N, int K, int lda, int ldb,
    size_t sA, size_t sB, size_t sC)
{
  __shared__ __hip_bfloat16 As[2][256 * 64];
  __shared__ __hip_bfloat16 Bs[2][256 * 64];

  const int tid  = threadIdx.x;
  const int lane = tid & 63;
  const int wave = tid >> 6;
  const int wm   = (wave >> 2) * 128;
  const int wn   = (wave & 3) * 64;
  const int lm   = lane & 15;
  const int quad = lane >> 4;
  const int ch0  = (quad ^ (lm >> 1)) * 8;

  int bx, by;
  xcd_swizzle(bx, by);

  const size_t bz = blockIdx.z;
  A += bz * sA;
  B += bz * sB;
  const int m0 = by * 256;
  const int n0 = bx * 256;

  const int rr = tid >> 3;
  const int jg = ((tid & 7) ^ ((tid >> 4) & 7)) * 8;
  const __hip_bfloat16* Ag = A + (size_t)(m0 + rr) * lda + jg;
  const __hip_bfloat16* Bg = B + (size_t)(n0 + rr) * ldb + jg;

  const int nt = K >> 6;
  floatx4 acc[8][4] = {};

  auto stageA = [&](int db, int kk, int h) {   // 128x64 half-tile, 2 insts
    const int ro = h * 128;
    async_copy16(&As[db][(ro)      * 64 + tid * 8], Ag + kk + (size_t)(ro)      * lda);
    async_copy16(&As[db][(ro + 64) * 64 + tid * 8], Ag + kk + (size_t)(ro + 64) * lda);
  };
  auto stageB = [&](int db, int kk, int h) {
    const int ro = h * 128;
    async_copy16(&Bs[db][(ro)      * 64 + tid * 8], Bg + kk + (size_t)(ro)      * ldb);
    async_copy16(&Bs[db][(ro + 64) * 64 + tid * 8], Bg + kk + (size_t)(ro + 64) * ldb);
  };

  // Prologue: tile 0 fully + B of tile 1; wait tile 0 (oldest 8), keep B(1).
  stageA(0, 0, 0); stageA(0, 0, 1);
  stageB(0, 0, 0); stageB(0, 0, 1);
  if (nt > 1) {
    stageB(1, 64, 0); stageB(1, 64, 1);
    __builtin_amdgcn_sched_barrier(0);
    asm volatile("s_waitcnt vmcnt(4)");
  } else {
    __builtin_amdgcn_sched_barrier(0);
    asm volatile("s_waitcnt vmcnt(0)");
  }
  __builtin_amdgcn_s_barrier();

  for (int t = 0; t < nt; ++t) {
    const int buf = t & 1;
    const int kb  = t * 64;
    const __hip_bfloat16* Ab = &As[buf][(wm + lm) * 64];
    const __hip_bfloat16* Bb = &Bs[buf][(wn + lm) * 64];
    lds_cbf16* a0 = (lds_cbf16*)(Ab + ch0);
    lds_cbf16* a1 = (lds_cbf16*)(Ab + (ch0 ^ 32));
    lds_cbf16* b0 = (lds_cbf16*)(Bb + ch0);
    lds_cbf16* b1 = (lds_cbf16*)(Bb + (ch0 ^ 32));
    short8 fb[2][4], faA[2][2], faB[2][2];

    // ---- top of tile: P1 burst reads + A(t+1) BOTH halves (max cover)
    fb[0][0] = ds_read128<0>(b0);    fb[0][1] = ds_read128<2048>(b0);
    fb[0][2] = ds_read128<4096>(b0); fb[0][3] = ds_read128<6144>(b0);
    fb[1][0] = ds_read128<0>(b1);    fb[1][1] = ds_read128<2048>(b1);
    fb[1][2] = ds_read128<4096>(b1); fb[1][3] = ds_read128<6144>(b1);
    faA[0][0] = ds_read128<0>(a0);   faA[0][1] = ds_read128<2048>(a0);
    faA[1][0] = ds_read128<0>(a1);   faA[1][1] = ds_read128<2048>(a1);
    if (t + 1 < nt) { stageA(buf ^ 1, kb + 64, 0); stageA(buf ^ 1, kb + 64, 1); }

    wait_lgkm0();
    __builtin_amdgcn_s_setprio(1);
    mfma_quad<0>(acc, faA, fb);
    __builtin_amdgcn_s_setprio(0);
    // quad0 shadow: A frags mi{2,3}
    faB[0][0] = ds_read128<4096>(a0); faB[0][1] = ds_read128<6144>(a0);
    faB[1][0] = ds_read128<4096>(a1); faB[1][1] = ds_read128<6144>(a1);

    wait_lgkm0();
    __builtin_amdgcn_s_setprio(1);
    mfma_quad<2>(acc, faB, fb);
    __builtin_amdgcn_s_setprio(0);
    // quad1 shadow: A frags mi{4,5}
    faA[0][0] = ds_read128<8192>(a0); faA[0][1] = ds_read128<10240>(a0);
    faA[1][0] = ds_read128<8192>(a1); faA[1][1] = ds_read128<10240>(a1);

    __builtin_amdgcn_s_barrier();   // BARRIER-1: fb reads certified complete

    // B(t+2) BOTH halves immediately after the barrier (1.5-tile cover)
    if (t + 2 < nt) { stageB(buf, kb + 128, 0); stageB(buf, kb + 128, 1); }

    wait_lgkm0();
    __builtin_amdgcn_s_setprio(1);
    mfma_quad<4>(acc, faA, fb);
    __builtin_amdgcn_s_setprio(0);
    // quad2 shadow: A frags mi{6,7}
    faB[0][0] = ds_read128<12288>(a0); faB[0][1] = ds_read128<14336>(a0);
    faB[1][0] = ds_read128<12288>(a1); faB[1][1] = ds_read128<14336>(a1);

    wait_lgkm0();
    __builtin_amdgcn_s_setprio(1);
    mfma_quad<6>(acc, faB, fb);
    __builtin_amdgcn_s_setprio(0);

    // ---- tile boundary: counted per-wave wait, THEN barrier
    __builtin_amdgcn_sched_barrier(0);
    if (t + 2 < nt)      asm volatile("s_waitcnt vmcnt(4)");
    else if (t + 1 < nt) asm volatile("s_waitcnt vmcnt(0)");
    __builtin_amdgcn_s_barrier();
  }

  // C/D layout: col = lane&15, row = quad*4 + i  [m89 verified]
  if constexpr (EPI == 1) {
    __hip_bfloat16* C = (__hip_bfloat16*)Cout + bz * sC;
    float* rs = rowsum + bz * (size_t)M;
    float ps[8][4];
#pragma unroll
    for (int mi = 0; mi < 8; mi++)
#pragma unroll
      for (int i = 0; i < 4; i++) ps[mi][i] = 0.0f;
#pragma unroll
    for (int mi = 0; mi < 8; mi++)
#pragma unroll
      for (int ni = 0; ni < 4; ni++) {
        const int col = n0 + wn + ni * 16 + lm;
#pragma unroll
        for (int i = 0; i < 4; i++) {
          const int row = m0 + wm + mi * 16 + quad * 4 + i;
          const float e = __expf(acc[mi][ni][i] * 0.03125f);
          C[(size_t)row * N + col] = (__hip_bfloat16)e;
          ps[mi][i] += e;
        }
      }
#pragma unroll
    for (int mi = 0; mi < 8; mi++)
#pragma unroll
      for (int i = 0; i < 4; i++) {
        float s = ps[mi][i];
        s += __shfl_xor(s, 1);
        s += __shfl_xor(s, 2);
        s += __shfl_xor(s, 4);
        s += __shfl_xor(s, 8);
        if (lm == 0) {
          const int row = m0 + wm + mi * 16 + quad * 4 + i;
          atomicAdd(&rs[row], s);
        }
      }
  } else {
    __hip_bfloat16* C = (__hip_bfloat16*)Cout + bz * sC;
#pragma unroll
    for (int ni = 0; ni < 4; ni++) {
      const int col = n0 + wn + ni * 16 + lm;
      const float bv = (float)bias[col];
#pragma unroll
      for (int mi = 0; mi < 8; mi++)
#pragma unroll
        for (int i = 0; i < 4; i++) {
          const int row = m0 + wm + mi * 16 + quad * 4 + i;
          C[(size_t)row * N + col] = (__hip_bfloat16)(acc[mi][ni][i] + bv);
        }
    }
  }
}

// ---------------------------------------------------------------------------
// NT GEMM, 128x256 tile, BK=64, 8 waves (2M x 4N), wave tile 64x64
// (acc[4][4]), 2 MFMA quads per K-tile, 2 barriers per K-tile, round-5
// prefetch timing: stage A(t+1) at top of tile (full-tile cover);
// stage B(t+2) right after BARRIER-1.
// Ring at boundary: outstanding 10 = B(t+1)4+A(t+1)2+B(t+2)4 -> vmcnt(4).
// 256-WG grid for PV (N=1024). LDS 96 KiB. EPI 2 = acc/rowsum[row] -> fp32.
// ---------------------------------------------------------------------------
template<int EPI>
__global__ __launch_bounds__(512, 2) void gemm128(
    const __hip_bfloat16* __restrict__ A,
    const __hip_bfloat16* __restrict__ B,
    float* __restrict__ rowsum,
    void* __restrict__ Cout,
    int M, int N, int K, int lda, int ldb,
    size_t sA, size_t sB, size_t sC)
{
  __shared__ __hip_bfloat16 As[2][128 * 64];
  __shared__ __hip_bfloat16 Bs[2][256 * 64];

  const int tid  = threadIdx.x;
  const int lane = tid & 63;
  const int wave = tid >> 6;
  const int wm   = (wave >> 2) * 64;
  const int wn   = (wave & 3) * 64;
  const int lm   = lane & 15;
  const int quad = lane >> 4;
  const int ch0  = (quad ^ (lm >> 1)) * 8;

  int bx, by;
  xcd_swizzle(bx, by);

  const size_t bz = blockIdx.z;
  A += bz * sA;
  B += bz * sB;
  const int m0 = by * 128;
  const int n0 = bx * 256;

  const int rr = tid >> 3;
  const int jg = ((tid & 7) ^ ((tid >> 4) & 7)) * 8;
  const __hip_bfloat16* Ag = A + (size_t)(m0 + rr) * lda + jg;
  const __hip_bfloat16* Bg = B + (size_t)(n0 + rr) * ldb + jg;

  const int nt = K >> 6;
  floatx4 acc[4][4] = {};

  auto stageA = [&](int db, int kk) {          // 128x64 tile, 2 insts
    async_copy16(&As[db][tid * 8],        Ag + kk);
    async_copy16(&As[db][4096 + tid * 8], Ag + kk + (size_t)64 * lda);
  };
  auto stageB = [&](int db, int kk) {          // 256x64 tile, 4 insts
#pragma unroll
    for (int g = 0; g < 4; g++)
      async_copy16(&Bs[db][g * 4096 + tid * 8], Bg + kk + (size_t)(g * 64) * ldb);
  };

  stageA(0, 0);
  stageB(0, 0);
  if (nt > 1) {
    stageB(1, 64);
    __builtin_amdgcn_sched_barrier(0);
    asm volatile("s_waitcnt vmcnt(4)");
  } else {
    __builtin_amdgcn_sched_barrier(0);
    asm volatile("s_waitcnt vmcnt(0)");
  }
  __builtin_amdgcn_s_barrier();

  for (int t = 0; t < nt; ++t) {
    const int buf = t & 1;
    const int kb  = t * 64;
    const __hip_bfloat16* Ab = &As[buf][(wm + lm) * 64];
    const __hip_bfloat16* Bb = &Bs[buf][(wn + lm) * 64];
    lds_cbf16* a0 = (lds_cbf16*)(Ab + ch0);
    lds_cbf16* a1 = (lds_cbf16*)(Ab + (ch0 ^ 32));
    lds_cbf16* b0 = (lds_cbf16*)(Bb + ch0);
    lds_cbf16* b1 = (lds_cbf16*)(Bb + (ch0 ^ 32));
    short8 fb[2][4], faA[2][2], faB[2][2];

    // top of tile: burst reads + A(t+1) stage (full-tile cover)
    fb[0][0] = ds_read128<0>(b0);    fb[0][1] = ds_read128<2048>(b0);
    fb[0][2] = ds_read128<4096>(b0); fb[0][3] = ds_read128<6144>(b0);
    fb[1][0] = ds_read128<0>(b1);    fb[1][1] = ds_read128<2048>(b1);
    fb[1][2] = ds_read128<4096>(b1); fb[1][3] = ds_read128<6144>(b1);
    faA[0][0] = ds_read128<0>(a0);   faA[0][1] = ds_read128<2048>(a0);
    faA[1][0] = ds_read128<0>(a1);   faA[1][1] = ds_read128<2048>(a1);
    if (t + 1 < nt) stageA(buf ^ 1, kb + 64);

    wait_lgkm0();
    __builtin_amdgcn_s_setprio(1);
    mfma_quad<0>(acc, faA, fb);
    __builtin_amdgcn_s_setprio(0);
    faB[0][0] = ds_read128<4096>(a0); faB[0][1] = ds_read128<6144>(a0);
    faB[1][0] = ds_read128<4096>(a1); faB[1][1] = ds_read128<6144>(a1);

    __builtin_amdgcn_s_barrier();   // BARRIER-1: fb reads certified complete

    if (t + 2 < nt) stageB(buf, kb + 128);

    wait_lgkm0();
    __builtin_amdgcn_s_setprio(1);
    mfma_quad<2>(acc, faB, fb);
    __builtin_amdgcn_s_setprio(0);

    __builtin_amdgcn_sched_barrier(0);
    if (t + 2 < nt)      asm volatile("s_waitcnt vmcnt(4)");
    else if (t + 1 < nt) asm volatile("s_waitcnt vmcnt(0)");
    __builtin_amdgcn_s_barrier();
  }

  if constexpr (EPI == 2) {
    float* C = (float*)Cout + bz * sC;
    const float* rs = rowsum + bz * (size_t)M;
#pragma unroll
    for (int mi = 0; mi < 4; mi++)
#pragma unroll
      for (int i = 0; i < 4; i++) {
        const int row = m0 + wm + mi * 16 + quad * 4 + i;
        const float rv = 1.0f / rs[row];
#pragma unroll
        for (int ni = 0; ni < 4; ni++) {
          const int col = n0 + wn + ni * 16 + lm;
          C[(size_t)row * N + col] = acc[mi][ni][i] * rv;
        }
      }
  }
}

// ---------------------------------------------------------------------------
// vT[b][e][s] = qkv[b][s][2048 + e]
// ---------------------------------------------------------------------------
__global__ __launch_bounds__(256) void transpose_v(
    const __hip_bfloat16* __restrict__ qkv, __hip_bfloat16* __restrict__ vT)
{
  __shared__ unsigned short t[64][68];
  const size_t bz = blockIdx.z;
  const unsigned short* src = (const unsigned short*)(qkv + bz * (size_t)SEQ * LDQ + 2048);
  unsigned short* dst = (unsigned short*)(vT + bz * (size_t)DIM * SEQ);
  const int e0 = blockIdx.x * 64;
  const int s0 = blockIdx.y * 64;
  const int tid = threadIdx.x;
  const int tr = tid >> 4;
  const int tc = (tid & 15) * 4;

#pragma unroll
  for (int i = 0; i < 4; i++) {
    const int row = tr + i * 16;
    ushortx4 val = *(const ushortx4*)(src + (size_t)(s0 + row) * LDQ + e0 + tc);
    t[row][tc + 0] = val.x; t[row][tc + 1] = val.y;
    t[row][tc + 2] = val.z; t[row][tc + 3] = val.w;
  }
  __syncthreads();
#pragma unroll
  for (int i = 0; i < 4; i++) {
    const int row = tr + i * 16;
    ushortx4 val;
    val.x = t[tc + 0][row]; val.y = t[tc + 1][row];
    val.z = t[tc + 2][row]; val.w = t[tc + 3][row];
    *(ushortx4*)(dst + (size_t)(e0 + row) * SEQ + s0 + tc) = val;
  }
}

// ---------------------------------------------------------------------------
extern "C" void kernel_launch(void* const* d_in, const int* in_sizes, int n_in,
                              void* d_out, int out_size, void* d_ws, size_t ws_size,
                              hipStream_t stream) {
  char* ws = (char*)d_ws;
  const size_t MB = 1024 * 1024;

  __hip_bfloat16* xc     = (__hip_bfloat16*)(ws + 1 * MB);   // 16 MB [1,17)
  __hip_bfloat16* Wc     = (__hip_bfloat16*)(ws + 17 * MB);  // 6 MB  [17,23)
  __hip_bfloat16* bc     = (__hip_bfloat16*)(ws + 23 * MB);  // 6 KB
  __hip_bfloat16* P      = (__hip_bfloat16*)(ws + 1 * MB);   // 32 MB [1,33) (after QKV)
  __hip_bfloat16* qkv    = (__hip_bfloat16*)(ws + 33 * MB);  // 48 MB [33,81)
  __hip_bfloat16* vT     = (__hip_bfloat16*)(ws + 81 * MB);  // 16 MB [81,97)
  float*          rowsum = (float*)(ws + 97 * MB);           // 32 KB
  float*          out    = (float*)d_out;

  const int NT = BATCH * SEQ;  // 8192

  canonize_all<<<dim3(5639), 256, 0, stream>>>(
      d_in[0], d_in[1], d_in[3], d_in[5], d_in[2], d_in[4], d_in[6],
      xc, Wc, bc, rowsum);

  // Fused QKV projection: [8192 x 3072] = x @ [Wq;Wk;Wv]^T + [bq;bk;bv]
  gemm256<0><<<dim3(3 * DIM / 256, NT / 256, 1), 512, 0, stream>>>(
      xc, Wc, bc, nullptr, qkv, NT, 3 * DIM, DIM, DIM, DIM, 0, 0, 0);

  transpose_v<<<dim3(DIM / 64, SEQ / 64, BATCH), 256, 0, stream>>>(qkv, vT);

  // P[b] = exp(q[b] @ k[b]^T / 32), rowsum accumulated in epilogue
  gemm256<1><<<dim3(SEQ / 256, SEQ / 256, BATCH), 512, 0, stream>>>(
      qkv /*q*/, qkv + DIM /*k*/, nullptr, rowsum, P, SEQ, SEQ, DIM, LDQ, LDQ,
      (size_t)SEQ * LDQ, (size_t)SEQ * LDQ, (size_t)SEQ * SEQ);

  // out[b] = (P[b] @ v[b]) / rowsum — 128x256 tile -> 4x16x4 = 256 WGs
  gemm128<2><<<dim3(DIM / 256, SEQ / 128, BATCH), 512, 0, stream>>>(
      P, vT, rowsum, out, SEQ, DIM, SEQ, SEQ, SEQ,
      (size_t)SEQ * SEQ, (size_t)DIM * SEQ, (size_t)SEQ * DIM);
}

// Round 6
// 241.367 us; speedup vs baseline: 1.0589x; 1.0589x over previous
//
#include <hip/hip_runtime.h>
#include <hip/hip_bf16.h>
#include <stdint.h>

typedef __attribute__((ext_vector_type(8)))  short short8;
typedef __attribute__((ext_vector_type(8)))  unsigned short ushort8;
typedef __attribute__((ext_vector_type(4)))  float floatx4;
typedef __attribute__((ext_vector_type(4)))  int intx4;
typedef __attribute__((ext_vector_type(4)))  unsigned short ushortx4;

static constexpr int BATCH = 4;
static constexpr int SEQ   = 2048;
static constexpr int DIM   = 1024;
static constexpr int LDQ   = 3 * DIM;  // qkv row stride

typedef __attribute__((address_space(1))) unsigned int gas_u32;
typedef __attribute__((address_space(3))) unsigned int las_u32;
typedef __attribute__((address_space(3))) const __hip_bfloat16 lds_cbf16;

__device__ __forceinline__ void async_copy16(void* lds, const void* g) {
  __builtin_amdgcn_global_load_lds((const gas_u32*)g, (las_u32*)lds, 16, 0, 0);
}

// Inline-asm ds_read_b128: invisible to backend waitcnt insertion (keeps the
// global_load_lds ring in flight). No "memory" clobbers anywhere in the hot
// loop (round-2 lesson: clobber => conservative vmcnt(0) drain per phase).
template<int OFF>
__device__ __forceinline__ short8 ds_read128(lds_cbf16* p) {
  short8 r;
  asm volatile("ds_read_b128 %0, %1 offset:%2" : "=v"(r) : "v"(p), "i"(OFF));
  return r;
}

__device__ __forceinline__ void wait_lgkm0() {
  asm volatile("s_waitcnt lgkmcnt(0)");     // bare: no memory clobber
  __builtin_amdgcn_sched_barrier(0);        // rule #18: pin MFMA behind wait
}

// T1: bijective XCD-aware block swizzle (m204). Only applied where each
// XCD's chunked working set L2-fits (scores/PV: 0.5-1MB panels). QKV's
// B-panel set is 6MB > 4MB L2 -> chunking thrashes (round-5: QKV +13us,
// FETCH evidence) -> QKV stays round-robin.
__device__ __forceinline__ void xcd_swizzle(int& bx, int& by) {
  const int gx  = gridDim.x;
  const int n   = gx * gridDim.y;
  const int bid = blockIdx.x + gx * blockIdx.y;
  const int q = n >> 3, r = n & 7;
  const int xcd = bid & 7, idx = bid >> 3;
  const int wg = (xcd < r) ? (xcd * (q + 1) + idx)
                           : (r * (q + 1) + (xcd - r) * q + idx);
  bx = wg % gx;
  by = wg / gx;
}

// ---------------------------------------------------------------------------
// Fused canonize (per-block fp32-vs-bf16 self-detection) + zero rowsum.
// ---------------------------------------------------------------------------
__global__ __launch_bounds__(256) void canonize_all(
    const void* __restrict__ s0, const void* __restrict__ s1,
    const void* __restrict__ s2, const void* __restrict__ s3,
    const void* __restrict__ s4, const void* __restrict__ s5,
    const void* __restrict__ s6,
    __hip_bfloat16* __restrict__ xc, __hip_bfloat16* __restrict__ Wc,
    __hip_bfloat16* __restrict__ bc, float* __restrict__ rowsum)
{
  int bid = blockIdx.x;
  if (bid >= 5635) {
    const int i = (bid - 5635) * 2048 + threadIdx.x * 8;
    intx4 z = {0, 0, 0, 0};
    *(intx4*)(rowsum + i)     = z;
    *(intx4*)(rowsum + i + 4) = z;
    return;
  }
  const void* src; __hip_bfloat16* dst; int n;
  if (bid < 4096)        { src = s0; dst = xc;            n = 8388608; }
  else if (bid < 4608)   { src = s1; dst = Wc;            n = 1048576; bid -= 4096; }
  else if (bid < 5120)   { src = s2; dst = Wc + 1048576;  n = 1048576; bid -= 4608; }
  else if (bid < 5632)   { src = s3; dst = Wc + 2097152;  n = 1048576; bid -= 5120; }
  else if (bid == 5632)  { src = s4; dst = bc;            n = 1024;    bid = 0; }
  else if (bid == 5633)  { src = s5; dst = bc + 1024;     n = 1024;    bid = 0; }
  else                   { src = s6; dst = bc + 2048;     n = 1024;    bid = 0; }

  __shared__ int cnt;
  if (threadIdx.x == 0) cnt = 0;
  __syncthreads();

  const int i = (bid * 256 + threadIdx.x) * 8;
  ushort8 v = {};
  int local = 0;
  if (i < n) {
    v = *(const ushort8*)((const unsigned short*)src + i);
#pragma unroll
    for (int j = 0; j < 8; j++) {
      unsigned e = (v[j] >> 7) & 0xFFu;
      local += (e >= 0x90u) ? 1 : 0;
    }
  }
  if (local) atomicAdd(&cnt, local);
  __syncthreads();
  if (i >= n) return;

  if (cnt > 4) {  // fp32 input: convert
    const float* s = (const float*)src + i;
    ushort8 o;
#pragma unroll
    for (int j = 0; j < 8; j++) {
      __hip_bfloat16 h = (__hip_bfloat16)s[j];
      o[j] = *(const unsigned short*)&h;
    }
    *(ushort8*)((unsigned short*)dst + i) = o;
  } else {        // already bf16: copy the probed data
    *(ushort8*)((unsigned short*)dst + i) = v;
  }
}

// ---------------------------------------------------------------------------
// 16-MFMA cluster: acc rows MI0,MI0+1 x 4 ni x 2 k-slices.
// ---------------------------------------------------------------------------
template<int MI0, int MR>
__device__ __forceinline__ void mfma_quad(floatx4 (&acc)[MR][4],
    const short8 (&fa)[2][2], const short8 (&fb)[2][4]) {
#pragma unroll
  for (int i = 0; i < 2; i++)
#pragma unroll
    for (int ni = 0; ni < 4; ni++)
#pragma unroll
      for (int ks = 0; ks < 2; ks++)
        acc[MI0 + i][ni] = __builtin_amdgcn_mfma_f32_16x16x32_bf16(
            fa[ks][i], fb[ks][ni], acc[MI0 + i][ni], 0, 0, 0);
}

// ---------------------------------------------------------------------------
// NT GEMM, 256x256 tile, BK=64, 512 threads = 8 waves (2M x 4N), per-wave
// 128x64 output, 4 MFMA quads per K-tile, TWO barriers per K-tile
// (round-4 staging placement, co-measured with best 71.6us):
//   P1 burst (fb8+faA4); quad0 [shadow: faB + stageA(t+1,h0)]
//   quad1 [shadow: faA2 + stageA(t+1,h1)]
//   BARRIER-1; quad2 [shadow: faB2 + stageB(t+2,h0)]
//   quad3; stageB(t+2,h1); sched_barrier; vmcnt(4); s_barrier
// WAR: stageA->buf^1 legal after t-1 boundary barrier; stageB->buf legal
// after BARRIER-1. RAW: per-wave vmcnt(4) BEFORE the boundary barrier
// (outstanding 12 = B(t+1)4+A(t+1)4+B(t+2)4 -> t+1 landed, B(t+2) flies).
// EPI: 0 = +bias[col] -> bf16 ; 1 = exp(acc/32) -> bf16 + rowsum atomics
// ---------------------------------------------------------------------------
template<int EPI, int SWZ>
__global__ __launch_bounds__(512, 2) void gemm256(
    const __hip_bfloat16* __restrict__ A,
    const __hip_bfloat16* __restrict__ B,
    const __hip_bfloat16* __restrict__ bias,
    float* __restrict__ rowsum,
    void* __restrict__ Cout,
    int M, int N, int K, int lda, int ldb,
    size_t sA, size_t sB, size_t sC)
{
  __shared__ __hip_bfloat16 As[2][256 * 64];
  __shared__ __hip_bfloat16 Bs[2][256 * 64];

  const int tid  = threadIdx.x;
  const int lane = tid & 63;
  const int wave = tid >> 6;
  const int wm   = (wave >> 2) * 128;
  const int wn   = (wave & 3) * 64;
  const int lm   = lane & 15;
  const int quad = lane >> 4;
  const int ch0  = (quad ^ (lm >> 1)) * 8;

  int bx, by;
  if constexpr (SWZ) xcd_swizzle(bx, by);
  else { bx = blockIdx.x; by = blockIdx.y; }

  const size_t bz = blockIdx.z;
  A += bz * sA;
  B += bz * sB;
  const int m0 = by * 256;
  const int n0 = bx * 256;

  const int rr = tid >> 3;
  const int jg = ((tid & 7) ^ ((tid >> 4) & 7)) * 8;
  const __hip_bfloat16* Ag = A + (size_t)(m0 + rr) * lda + jg;
  const __hip_bfloat16* Bg = B + (size_t)(n0 + rr) * ldb + jg;

  const int nt = K >> 6;
  floatx4 acc[8][4] = {};

  auto stageA = [&](int db, int kk, int h) {   // 128x64 half-tile, 2 insts
    const int ro = h * 128;
    async_copy16(&As[db][(ro)      * 64 + tid * 8], Ag + kk + (size_t)(ro)      * lda);
    async_copy16(&As[db][(ro + 64) * 64 + tid * 8], Ag + kk + (size_t)(ro + 64) * lda);
  };
  auto stageB = [&](int db, int kk, int h) {
    const int ro = h * 128;
    async_copy16(&Bs[db][(ro)      * 64 + tid * 8], Bg + kk + (size_t)(ro)      * ldb);
    async_copy16(&Bs[db][(ro + 64) * 64 + tid * 8], Bg + kk + (size_t)(ro + 64) * ldb);
  };

  // Prologue: tile 0 fully + B of tile 1; wait tile 0 (oldest 8), keep B(1).
  stageA(0, 0, 0); stageA(0, 0, 1);
  stageB(0, 0, 0); stageB(0, 0, 1);
  if (nt > 1) {
    stageB(1, 64, 0); stageB(1, 64, 1);
    __builtin_amdgcn_sched_barrier(0);
    asm volatile("s_waitcnt vmcnt(4)");
  } else {
    __builtin_amdgcn_sched_barrier(0);
    asm volatile("s_waitcnt vmcnt(0)");
  }
  __builtin_amdgcn_s_barrier();

  for (int t = 0; t < nt; ++t) {
    const int buf = t & 1;
    const int kb  = t * 64;
    const __hip_bfloat16* Ab = &As[buf][(wm + lm) * 64];
    const __hip_bfloat16* Bb = &Bs[buf][(wn + lm) * 64];
    lds_cbf16* a0 = (lds_cbf16*)(Ab + ch0);
    lds_cbf16* a1 = (lds_cbf16*)(Ab + (ch0 ^ 32));
    lds_cbf16* b0 = (lds_cbf16*)(Bb + ch0);
    lds_cbf16* b1 = (lds_cbf16*)(Bb + (ch0 ^ 32));
    short8 fb[2][4], faA[2][2], faB[2][2];

    // ---- P1 burst: all B frags + A(mi0,1)
    fb[0][0] = ds_read128<0>(b0);    fb[0][1] = ds_read128<2048>(b0);
    fb[0][2] = ds_read128<4096>(b0); fb[0][3] = ds_read128<6144>(b0);
    fb[1][0] = ds_read128<0>(b1);    fb[1][1] = ds_read128<2048>(b1);
    fb[1][2] = ds_read128<4096>(b1); fb[1][3] = ds_read128<6144>(b1);
    faA[0][0] = ds_read128<0>(a0);   faA[0][1] = ds_read128<2048>(a0);
    faA[1][0] = ds_read128<0>(a1);   faA[1][1] = ds_read128<2048>(a1);
    wait_lgkm0();
    __builtin_amdgcn_s_setprio(1);
    mfma_quad<0>(acc, faA, fb);
    __builtin_amdgcn_s_setprio(0);
    // quad0 shadow: A frags mi{2,3} + stageA half0
    faB[0][0] = ds_read128<4096>(a0); faB[0][1] = ds_read128<6144>(a0);
    faB[1][0] = ds_read128<4096>(a1); faB[1][1] = ds_read128<6144>(a1);
    if (t + 1 < nt) stageA(buf ^ 1, kb + 64, 0);

    wait_lgkm0();
    __builtin_amdgcn_s_setprio(1);
    mfma_quad<2>(acc, faB, fb);
    __builtin_amdgcn_s_setprio(0);
    // quad1 shadow: A frags mi{4,5} + stageA half1
    faA[0][0] = ds_read128<8192>(a0); faA[0][1] = ds_read128<10240>(a0);
    faA[1][0] = ds_read128<8192>(a1); faA[1][1] = ds_read128<10240>(a1);
    if (t + 1 < nt) stageA(buf ^ 1, kb + 64, 1);

    __builtin_amdgcn_s_barrier();   // BARRIER-1: fb reads certified complete

    wait_lgkm0();
    __builtin_amdgcn_s_setprio(1);
    mfma_quad<4>(acc, faA, fb);
    __builtin_amdgcn_s_setprio(0);
    // quad2 shadow: A frags mi{6,7} + stageB half0
    faB[0][0] = ds_read128<12288>(a0); faB[0][1] = ds_read128<14336>(a0);
    faB[1][0] = ds_read128<12288>(a1); faB[1][1] = ds_read128<14336>(a1);
    if (t + 2 < nt) stageB(buf, kb + 128, 0);

    wait_lgkm0();
    __builtin_amdgcn_s_setprio(1);
    mfma_quad<6>(acc, faB, fb);
    __builtin_amdgcn_s_setprio(0);
    if (t + 2 < nt) stageB(buf, kb + 128, 1);

    // ---- tile boundary: counted per-wave wait, THEN barrier
    __builtin_amdgcn_sched_barrier(0);
    if (t + 2 < nt)      asm volatile("s_waitcnt vmcnt(4)");
    else if (t + 1 < nt) asm volatile("s_waitcnt vmcnt(0)");
    __builtin_amdgcn_s_barrier();
  }

  // C/D layout: col = lane&15, row = quad*4 + i  [m89 verified]
  if constexpr (EPI == 1) {
    __hip_bfloat16* C = (__hip_bfloat16*)Cout + bz * sC;
    float* rs = rowsum + bz * (size_t)M;
    float ps[8][4];
#pragma unroll
    for (int mi = 0; mi < 8; mi++)
#pragma unroll
      for (int i = 0; i < 4; i++) ps[mi][i] = 0.0f;
#pragma unroll
    for (int mi = 0; mi < 8; mi++)
#pragma unroll
      for (int ni = 0; ni < 4; ni++) {
        const int col = n0 + wn + ni * 16 + lm;
#pragma unroll
        for (int i = 0; i < 4; i++) {
          const int row = m0 + wm + mi * 16 + quad * 4 + i;
          const float e = __expf(acc[mi][ni][i] * 0.03125f);
          C[(size_t)row * N + col] = (__hip_bfloat16)e;
          ps[mi][i] += e;
        }
      }
#pragma unroll
    for (int mi = 0; mi < 8; mi++)
#pragma unroll
      for (int i = 0; i < 4; i++) {
        float s = ps[mi][i];
        s += __shfl_xor(s, 1);
        s += __shfl_xor(s, 2);
        s += __shfl_xor(s, 4);
        s += __shfl_xor(s, 8);
        if (lm == 0) {
          const int row = m0 + wm + mi * 16 + quad * 4 + i;
          atomicAdd(&rs[row], s);
        }
      }
  } else {
    __hip_bfloat16* C = (__hip_bfloat16*)Cout + bz * sC;
#pragma unroll
    for (int ni = 0; ni < 4; ni++) {
      const int col = n0 + wn + ni * 16 + lm;
      const float bv = (float)bias[col];
#pragma unroll
      for (int mi = 0; mi < 8; mi++)
#pragma unroll
        for (int i = 0; i < 4; i++) {
          const int row = m0 + wm + mi * 16 + quad * 4 + i;
          C[(size_t)row * N + col] = (__hip_bfloat16)(acc[mi][ni][i] + bv);
        }
    }
  }
}

// ---------------------------------------------------------------------------
// NT GEMM, 128x256 tile, BK=64, 8 waves (2M x 4N), wave tile 64x64
// (acc[4][4]), 2 MFMA quads per K-tile, 2 barriers per K-tile.
// Used for QKV (EPI 0, SWZ 0: grid 12x64 = 768 = 3.0 exact CU rounds,
// kills the 256-tile 1.5-round quantization tail) and PV (EPI 2, SWZ 1).
// Ring at boundary: outstanding 10 = B(t+1)4+A(t+1)2+B(t+2)4 -> vmcnt(4).
// LDS 96 KiB. EPI: 0 = +bias -> bf16 ; 2 = acc/rowsum[row] -> fp32.
// ---------------------------------------------------------------------------
template<int EPI, int SWZ>
__global__ __launch_bounds__(512, 2) void gemm128(
    const __hip_bfloat16* __restrict__ A,
    const __hip_bfloat16* __restrict__ B,
    const __hip_bfloat16* __restrict__ bias,
    float* __restrict__ rowsum,
    void* __restrict__ Cout,
    int M, int N, int K, int lda, int ldb,
    size_t sA, size_t sB, size_t sC)
{
  __shared__ __hip_bfloat16 As[2][128 * 64];
  __shared__ __hip_bfloat16 Bs[2][256 * 64];

  const int tid  = threadIdx.x;
  const int lane = tid & 63;
  const int wave = tid >> 6;
  const int wm   = (wave >> 2) * 64;
  const int wn   = (wave & 3) * 64;
  const int lm   = lane & 15;
  const int quad = lane >> 4;
  const int ch0  = (quad ^ (lm >> 1)) * 8;

  int bx, by;
  if constexpr (SWZ) xcd_swizzle(bx, by);
  else { bx = blockIdx.x; by = blockIdx.y; }

  const size_t bz = blockIdx.z;
  A += bz * sA;
  B += bz * sB;
  const int m0 = by * 128;
  const int n0 = bx * 256;

  const int rr = tid >> 3;
  const int jg = ((tid & 7) ^ ((tid >> 4) & 7)) * 8;
  const __hip_bfloat16* Ag = A + (size_t)(m0 + rr) * lda + jg;
  const __hip_bfloat16* Bg = B + (size_t)(n0 + rr) * ldb + jg;

  const int nt = K >> 6;
  floatx4 acc[4][4] = {};

  auto stageA = [&](int db, int kk) {          // 128x64 tile, 2 insts
    async_copy16(&As[db][tid * 8],        Ag + kk);
    async_copy16(&As[db][4096 + tid * 8], Ag + kk + (size_t)64 * lda);
  };
  auto stageB = [&](int db, int kk) {          // 256x64 tile, 4 insts
#pragma unroll
    for (int g = 0; g < 4; g++)
      async_copy16(&Bs[db][g * 4096 + tid * 8], Bg + kk + (size_t)(g * 64) * ldb);
  };

  stageA(0, 0);
  stageB(0, 0);
  if (nt > 1) {
    stageB(1, 64);
    __builtin_amdgcn_sched_barrier(0);
    asm volatile("s_waitcnt vmcnt(4)");
  } else {
    __builtin_amdgcn_sched_barrier(0);
    asm volatile("s_waitcnt vmcnt(0)");
  }
  __builtin_amdgcn_s_barrier();

  for (int t = 0; t < nt; ++t) {
    const int buf = t & 1;
    const int kb  = t * 64;
    const __hip_bfloat16* Ab = &As[buf][(wm + lm) * 64];
    const __hip_bfloat16* Bb = &Bs[buf][(wn + lm) * 64];
    lds_cbf16* a0 = (lds_cbf16*)(Ab + ch0);
    lds_cbf16* a1 = (lds_cbf16*)(Ab + (ch0 ^ 32));
    lds_cbf16* b0 = (lds_cbf16*)(Bb + ch0);
    lds_cbf16* b1 = (lds_cbf16*)(Bb + (ch0 ^ 32));
    short8 fb[2][4], faA[2][2], faB[2][2];

    // top of tile: burst reads + A(t+1) stage (full-tile cover)
    fb[0][0] = ds_read128<0>(b0);    fb[0][1] = ds_read128<2048>(b0);
    fb[0][2] = ds_read128<4096>(b0); fb[0][3] = ds_read128<6144>(b0);
    fb[1][0] = ds_read128<0>(b1);    fb[1][1] = ds_read128<2048>(b1);
    fb[1][2] = ds_read128<4096>(b1); fb[1][3] = ds_read128<6144>(b1);
    faA[0][0] = ds_read128<0>(a0);   faA[0][1] = ds_read128<2048>(a0);
    faA[1][0] = ds_read128<0>(a1);   faA[1][1] = ds_read128<2048>(a1);
    if (t + 1 < nt) stageA(buf ^ 1, kb + 64);

    wait_lgkm0();
    __builtin_amdgcn_s_setprio(1);
    mfma_quad<0>(acc, faA, fb);
    __builtin_amdgcn_s_setprio(0);
    faB[0][0] = ds_read128<4096>(a0); faB[0][1] = ds_read128<6144>(a0);
    faB[1][0] = ds_read128<4096>(a1); faB[1][1] = ds_read128<6144>(a1);

    __builtin_amdgcn_s_barrier();   // BARRIER-1: fb reads certified complete

    if (t + 2 < nt) stageB(buf, kb + 128);

    wait_lgkm0();
    __builtin_amdgcn_s_setprio(1);
    mfma_quad<2>(acc, faB, fb);
    __builtin_amdgcn_s_setprio(0);

    __builtin_amdgcn_sched_barrier(0);
    if (t + 2 < nt)      asm volatile("s_waitcnt vmcnt(4)");
    else if (t + 1 < nt) asm volatile("s_waitcnt vmcnt(0)");
    __builtin_amdgcn_s_barrier();
  }

  if constexpr (EPI == 2) {
    float* C = (float*)Cout + bz * sC;
    const float* rs = rowsum + bz * (size_t)M;
#pragma unroll
    for (int mi = 0; mi < 4; mi++)
#pragma unroll
      for (int i = 0; i < 4; i++) {
        const int row = m0 + wm + mi * 16 + quad * 4 + i;
        const float rv = 1.0f / rs[row];
#pragma unroll
        for (int ni = 0; ni < 4; ni++) {
          const int col = n0 + wn + ni * 16 + lm;
          C[(size_t)row * N + col] = acc[mi][ni][i] * rv;
        }
      }
  } else {
    __hip_bfloat16* C = (__hip_bfloat16*)Cout + bz * sC;
#pragma unroll
    for (int ni = 0; ni < 4; ni++) {
      const int col = n0 + wn + ni * 16 + lm;
      const float bv = (float)bias[col];
#pragma unroll
      for (int mi = 0; mi < 4; mi++)
#pragma unroll
        for (int i = 0; i < 4; i++) {
          const int row = m0 + wm + mi * 16 + quad * 4 + i;
          C[(size_t)row * N + col] = (__hip_bfloat16)(acc[mi][ni][i] + bv);
        }
    }
  }
}

// ---------------------------------------------------------------------------
// vT[b][e][s] = qkv[b][s][2048 + e]
// ---------------------------------------------------------------------------
__global__ __launch_bounds__(256) void transpose_v(
    const __hip_bfloat16* __restrict__ qkv, __hip_bfloat16* __restrict__ vT)
{
  __shared__ unsigned short t[64][68];
  const size_t bz = blockIdx.z;
  const unsigned short* src = (const unsigned short*)(qkv + bz * (size_t)SEQ * LDQ + 2048);
  unsigned short* dst = (unsigned short*)(vT + bz * (size_t)DIM * SEQ);
  const int e0 = blockIdx.x * 64;
  const int s0 = blockIdx.y * 64;
  const int tid = threadIdx.x;
  const int tr = tid >> 4;
  const int tc = (tid & 15) * 4;

#pragma unroll
  for (int i = 0; i < 4; i++) {
    const int row = tr + i * 16;
    ushortx4 val = *(const ushortx4*)(src + (size_t)(s0 + row) * LDQ + e0 + tc);
    t[row][tc + 0] = val.x; t[row][tc + 1] = val.y;
    t[row][tc + 2] = val.z; t[row][tc + 3] = val.w;
  }
  __syncthreads();
#pragma unroll
  for (int i = 0; i < 4; i++) {
    const int row = tr + i * 16;
    ushortx4 val;
    val.x = t[tc + 0][row]; val.y = t[tc + 1][row];
    val.z = t[tc + 2][row]; val.w = t[tc + 3][row];
    *(ushortx4*)(dst + (size_t)(e0 + row) * SEQ + s0 + tc) = val;
  }
}

// ---------------------------------------------------------------------------
extern "C" void kernel_launch(void* const* d_in, const int* in_sizes, int n_in,
                              void* d_out, int out_size, void* d_ws, size_t ws_size,
                              hipStream_t stream) {
  char* ws = (char*)d_ws;
  const size_t MB = 1024 * 1024;

  __hip_bfloat16* xc     = (__hip_bfloat16*)(ws + 1 * MB);   // 16 MB [1,17)
  __hip_bfloat16* Wc     = (__hip_bfloat16*)(ws + 17 * MB);  // 6 MB  [17,23)
  __hip_bfloat16* bc     = (__hip_bfloat16*)(ws + 23 * MB);  // 6 KB
  __hip_bfloat16* P      = (__hip_bfloat16*)(ws + 1 * MB);   // 32 MB [1,33) (after QKV)
  __hip_bfloat16* qkv    = (__hip_bfloat16*)(ws + 33 * MB);  // 48 MB [33,81)
  __hip_bfloat16* vT     = (__hip_bfloat16*)(ws + 81 * MB);  // 16 MB [81,97)
  float*          rowsum = (float*)(ws + 97 * MB);           // 32 KB
  float*          out    = (float*)d_out;

  const int NT = BATCH * SEQ;  // 8192

  canonize_all<<<dim3(5639), 256, 0, stream>>>(
      d_in[0], d_in[1], d_in[3], d_in[5], d_in[2], d_in[4], d_in[6],
      xc, Wc, bc, rowsum);

  // Fused QKV projection: [8192 x 3072] = x @ [Wq;Wk;Wv]^T + [bq;bk;bv]
  // 128x256 tile -> 12x64 = 768 blocks = 3.0 exact CU rounds (no tail).
  gemm128<0, 0><<<dim3(3 * DIM / 256, NT / 128, 1), 512, 0, stream>>>(
      xc, Wc, bc, nullptr, qkv, NT, 3 * DIM, DIM, DIM, DIM, 0, 0, 0);

  transpose_v<<<dim3(DIM / 64, SEQ / 64, BATCH), 256, 0, stream>>>(qkv, vT);

  // P[b] = exp(q[b] @ k[b]^T / 32), rowsum accumulated in epilogue
  gemm256<1, 1><<<dim3(SEQ / 256, SEQ / 256, BATCH), 512, 0, stream>>>(
      qkv /*q*/, qkv + DIM /*k*/, nullptr, rowsum, P, SEQ, SEQ, DIM, LDQ, LDQ,
      (size_t)SEQ * LDQ, (size_t)SEQ * LDQ, (size_t)SEQ * SEQ);

  // out[b] = (P[b] @ v[b]) / rowsum — 128x256 tile -> 4x16x4 = 256 WGs
  gemm128<2, 1><<<dim3(DIM / 256, SEQ / 128, BATCH), 512, 0, stream>>>(
      P, vT, nullptr, rowsum, out, SEQ, DIM, SEQ, SEQ, SEQ,
      (size_t)SEQ * SEQ, (size_t)DIM * SEQ, (size_t)SEQ * DIM);
}